// Round 5
// baseline (479.282 us; speedup 1.0000x reference)
//
#include <hip/hip_runtime.h>
#include <hip/hip_bf16.h>
#include <stdint.h>

typedef __hip_bfloat16 bf16;
typedef __hip_bfloat162 bf162;

typedef __attribute__((ext_vector_type(8))) short short8;   // 8 bf16 = 4 VGPRs
typedef __attribute__((ext_vector_type(4))) float floatx4;  // MFMA accumulator

#define BSH   8        // bucket = 256 nodes
#define BSZ   256
#define CHUNK 8192     // edges per sort block
#define NBMAX 512      // max buckets supported (N <= 131072)
#define NSLAB 8        // feature slabs (= XCD count); slab = 16 feats = 32 B

// Feature-sliced ("slab") layout for all bf16 feature matrices:
//   addr(node n, feature f) = slab(f>>4) * N * 16 + n * 16 + (f & 15)
// One slab = N x 32 B = 3.2 MB -> fits a single XCD's 4 MB L2.
// agg blocks pin slab = blockIdx.x % 8 (XCD round-robin) so each XCD's
// random gather hits only its own L2-resident slab.

// ---------------- helpers ----------------

__device__ __forceinline__ void acc2(float& a, float& b, unsigned u) {
    a += __uint_as_float(u << 16);
    b += __uint_as_float(u & 0xffff0000u);
}

// ---------------- prep + bhist (single dispatch) ----------------
// blocks [0, nCvt):        x (row-major f32) -> xbf (slab bf16)
// blocks [nCvt, nCvt+48):  weights -> B-fragment layout for mfma_f32_16x16x32_bf16
// blocks [nCvt+48, ...):   per-chunk bucket histogram of dst
__global__ __launch_bounds__(256)
void prep_bhist_kernel(const float* __restrict__ x, bf16* __restrict__ y, int n4, int nCvt,
                       const float* __restrict__ wr1, const float* __restrict__ wo1,
                       const float* __restrict__ wr2, const float* __restrict__ wo2,
                       const float* __restrict__ wr3, const float* __restrict__ wo3,
                       bf16* __restrict__ w1, bf16* __restrict__ w2, bf16* __restrict__ w3,
                       const int* __restrict__ dst, int* __restrict__ T,
                       int E, int NB, int GB) {
    __shared__ int lh[NBMAX];
    const int b = blockIdx.x;
    if (b < nCvt) {
        const int i = b * 256 + threadIdx.x;
        if (i < n4) {
            const int N = n4 >> 5;
            const int n = i >> 5;
            const int q = i & 31;          // features 4q..4q+3
            float4 v = ((const float4*)x)[i];
            union { bf16 bb[4]; unsigned long long u; } pk;
            pk.bb[0] = __float2bfloat16(v.x);
            pk.bb[1] = __float2bfloat16(v.y);
            pk.bb[2] = __float2bfloat16(v.z);
            pk.bb[3] = __float2bfloat16(v.w);
            *(unsigned long long*)(y + ((size_t)(q >> 2) * N + n) * 16 + (q & 3) * 4) = pk.u;
        }
        return;
    }
    if (b < nCvt + 48) {
        int t = (b - nCvt) * 256 + threadIdx.x;       // 0..12287
        const int layer = t >> 12;
        t &= 4095;
        const float* wrel  = (layer == 0) ? wr1 : (layer == 1) ? wr2 : wr3;
        const float* wroot = (layer == 0) ? wo1 : (layer == 1) ? wo2 : wo3;
        bf16*        wsw   = (layer == 0) ? w1  : (layer == 1) ? w2  : w3;
        const int lane = t & 63;
        const int ct   = (t >> 6) & 7;
        const int kt   = t >> 9;
        const int kbase = kt * 32 + (lane >> 4) * 8;
        const int n     = ct * 16 + (lane & 15);
        bf16* q = wsw + (size_t)t * 8;
#pragma unroll
        for (int j = 0; j < 8; ++j) {
            const int k = kbase + j;
            const float v = (k < 128) ? wrel[k * 128 + n] : wroot[(k - 128) * 128 + n];
            q[j] = __float2bfloat16(v);
        }
        return;
    }
    // ---- bhist ----
    const int bb = b - nCvt - 48;
    for (int u = threadIdx.x; u < NB; u += 256) lh[u] = 0;
    __syncthreads();
    const int beg = bb * CHUNK, end = min(beg + CHUNK, E);
    for (int e = beg + threadIdx.x; e < end; e += 256)
        atomicAdd(&lh[dst[e] >> BSH], 1);
    __syncthreads();
    for (int u = threadIdx.x; u < NB; u += 256)
        T[u * GB + bb] = lh[u];
}

// ---------------- CSR build: two-level counting sort ----------------

__global__ __launch_bounds__(256)
void scan1_kernel(const int* __restrict__ deg, int* __restrict__ rp,
                  int* __restrict__ bsum, int n) {
    __shared__ int s[256];
    const int tid = threadIdx.x;
    const int i = blockIdx.x * 256 + tid;
    const int d = (i < n) ? deg[i] : 0;
    s[tid] = d;
    __syncthreads();
    for (int off = 1; off < 256; off <<= 1) {
        int u = (tid >= off) ? s[tid - off] : 0;
        __syncthreads();
        s[tid] += u;
        __syncthreads();
    }
    if (i < n) rp[i] = s[tid] - d;
    if (tid == 255) bsum[blockIdx.x] = s[255];
}

__global__ __launch_bounds__(512)
void scan2_kernel(int* __restrict__ bsum, int G) {
    __shared__ int s[512];
    const int tid = threadIdx.x;
    const int d = (tid < G) ? bsum[tid] : 0;
    s[tid] = d;
    __syncthreads();
    for (int off = 1; off < 512; off <<= 1) {
        int u = (tid >= off) ? s[tid - off] : 0;
        __syncthreads();
        s[tid] += u;
        __syncthreads();
    }
    if (tid < G) bsum[tid] = s[tid] - d;
}

// scan3 folded into the two consumers: Tfinal[i] = T[i] + bsum[i >> 8]

__global__ __launch_bounds__(256)
void bscatter_kernel(const int* __restrict__ src, const int* __restrict__ dst,
                     const int* __restrict__ T, const int* __restrict__ bsum,
                     int* __restrict__ ebuf, int E, int NB, int GB) {
    __shared__ int lofs[NBMAX];
    const int b = blockIdx.x;
    for (int u = threadIdx.x; u < NB; u += 256) {
        const int idx = u * GB + b;
        lofs[u] = T[idx] + bsum[idx >> 8];
    }
    __syncthreads();
    const int beg = b * CHUNK, end = min(beg + CHUNK, E);
    for (int e = beg + threadIdx.x; e < end; e += 256) {
        const int d = dst[e];
        const int u = d >> BSH;
        const int pos = atomicAdd(&lofs[u], 1);
        ebuf[pos] = (src[e] << BSH) | (d & (BSZ - 1));
    }
}

__global__ __launch_bounds__(256)
void bbuild_kernel(const int* __restrict__ T, const int* __restrict__ bsum,
                   const int* __restrict__ ebuf,
                   int* __restrict__ rp, int* __restrict__ col,
                   int E, int N, int NB, int GB) {
    __shared__ int s[256];
    __shared__ int lrank[256];
    const int u = blockIdx.x;
    const int tid = threadIdx.x;
    const int i0 = u * GB;
    const int beg = T[i0] + bsum[i0 >> 8];
    const int i1 = (u + 1) * GB;
    const int end = (u + 1 < NB) ? (T[i1] + bsum[i1 >> 8]) : E;

    lrank[tid] = 0;
    __syncthreads();
    for (int e = beg + tid; e < end; e += 256)
        atomicAdd(&lrank[ebuf[e] & (BSZ - 1)], 1);
    __syncthreads();
    const int cntv = lrank[tid];
    s[tid] = cntv;
    __syncthreads();
    for (int off = 1; off < 256; off <<= 1) {
        int v = (tid >= off) ? s[tid - off] : 0;
        __syncthreads();
        s[tid] += v;
        __syncthreads();
    }
    const int excl = s[tid] - cntv;
    const int node = u * BSZ + tid;
    if (node < N) rp[node] = beg + excl;
    if (u == NB - 1 && tid == 0) rp[N] = E;
    lrank[tid] = beg + excl;
    __syncthreads();
    for (int e = beg + tid; e < end; e += 256) {
        const int p = ebuf[e];
        const int pos = atomicAdd(&lrank[p & (BSZ - 1)], 1);
        col[pos] = p >> BSH;
    }
}

// ---------------- aggregation (slab-sliced, XCD-pinned) ----------------
// block: slab s = blockIdx.x % 8 (XCD round-robin), 128 nodes.
// wave = 16 groups x 4 lanes; each group owns ONE node and walks its edge
// list serially, gathering the 32 B slab slice per edge (lane = 8 B).
// Group-private loop => exec-mask handles degree tails, no cross-lane reduce.
// Each XCD's gather working set = its 3.2 MB slab -> L2-resident.
// agg written nontemporal to keep L2 dedicated to the slab.

__global__ __launch_bounds__(512)
void agg_kernel(const bf16* __restrict__ h, const int* __restrict__ rp,
                const int* __restrict__ col, bf16* __restrict__ agg, int N) {
    const int s    = blockIdx.x & 7;
    const int tid  = threadIdx.x;
    const int wid  = tid >> 6;
    const int lane = tid & 63;
    const int g    = lane >> 2;          // 16 node-groups per wave
    const int fl   = lane & 3;           // 8 B feature sub-chunk
    const int node = (blockIdx.x >> 3) * 128 + wid * 16 + g;
    if (node >= N) return;

    const bf16* Hs = h + (size_t)s * N * 16;
    const int beg = rp[node], end = rp[node + 1];

    float a0 = 0.f, a1 = 0.f, a2 = 0.f, a3 = 0.f;
    int e = beg;
#pragma unroll 2
    for (; e + 2 <= end; e += 2) {
        const int s0 = col[e];
        const int s1 = col[e + 1];
        const uint2 r0 = *(const uint2*)(Hs + (size_t)s0 * 16 + fl * 4);
        const uint2 r1 = *(const uint2*)(Hs + (size_t)s1 * 16 + fl * 4);
        acc2(a0, a1, r0.x); acc2(a2, a3, r0.y);
        acc2(a0, a1, r1.x); acc2(a2, a3, r1.y);
    }
    if (e < end) {
        const int s0 = col[e];
        const uint2 r0 = *(const uint2*)(Hs + (size_t)s0 * 16 + fl * 4);
        acc2(a0, a1, r0.x); acc2(a2, a3, r0.y);
    }

    union { bf16 bb[4]; unsigned long long u; } pk;
    pk.bb[0] = __float2bfloat16(a0);
    pk.bb[1] = __float2bfloat16(a1);
    pk.bb[2] = __float2bfloat16(a2);
    pk.bb[3] = __float2bfloat16(a3);
    __builtin_nontemporal_store(pk.u,
        (unsigned long long*)(agg + ((size_t)s * N + node) * 16 + fl * 4));
}

// ---------------- MFMA dual GEMM: out = [agg|h] @ Wsw + b (+relu) ----------------
// 512 threads, 128 rows/block; wsw staged once in LDS; epilogue via LDS tile.
// A-fragments read from slab layout: feature k0..k0+7 lives at
//   (k0>>4)*N*16 + row*16 + (k0&15)   ((k0&15) in {0,8} -> 16 B aligned).
// bf16 epilogue writes slab layout (contiguous 8 KB per slab per block);
// fp32 final epilogue writes row-major (external output).

template <bool RELU, typename OT>
__global__ __launch_bounds__(512)
void mfma_gemm_kernel(const bf16* __restrict__ Aagg, const bf16* __restrict__ Hroot,
                      const bf16* __restrict__ wsw, const float* __restrict__ bias,
                      OT* __restrict__ out, int M) {
    __shared__ __align__(16) char smem[67584];
    const int tid = threadIdx.x;

    // stage all B-fragments (65536 B) into LDS: 512 thr x 16 B x 8
#pragma unroll
    for (int i = 0; i < 8; ++i) {
        const int off = i * 8192 + tid * 16;
        *(float4*)(smem + off) = *(const float4*)((const char*)wsw + off);
    }
    __syncthreads();

    const int lane = tid & 63;
    const int wave = tid >> 6;
    const int l15  = lane & 15;
    const int quad = lane >> 4;
    const int base = blockIdx.x * 128;
    const int row_a = base + wave * 16 + l15;
    const bool rowok = row_a < M;
    const bf16* wl = (const bf16*)smem;

    floatx4 acc[8];
#pragma unroll
    for (int ct = 0; ct < 8; ++ct) acc[ct] = (floatx4){0.f, 0.f, 0.f, 0.f};

#pragma unroll
    for (int kt = 0; kt < 8; ++kt) {
        const bf16* Abase = (kt < 4) ? Aagg : Hroot;
        const int k0 = (kt & 3) * 32 + quad * 8;
        short8 afrag = (short8){0, 0, 0, 0, 0, 0, 0, 0};
        if (rowok)
            afrag = *(const short8*)(Abase + ((size_t)(k0 >> 4) * M + row_a) * 16 + (k0 & 15));
#pragma unroll
        for (int ct = 0; ct < 8; ++ct) {
            const short8 bfrag = *(const short8*)(wl + (size_t)((kt * 8 + ct) * 64 + lane) * 8);
            acc[ct] = __builtin_amdgcn_mfma_f32_16x16x32_bf16(afrag, bfrag, acc[ct], 0, 0, 0);
        }
    }

    __syncthreads();   // all waves done reading wl -> reuse smem as output tile
    const int rloc = wave * 16 + quad * 4;

    if constexpr (sizeof(OT) == 2) {
        bf16* tl = (bf16*)smem;                // stride 136 bf16 = 272 B
#pragma unroll
        for (int ct = 0; ct < 8; ++ct) {
            const int colc = ct * 16 + l15;
            const float bv = bias[colc];
#pragma unroll
            for (int r = 0; r < 4; ++r) {
                float v = acc[ct][r] + bv;
                if (RELU) v = fmaxf(v, 0.f);
                tl[(rloc + r) * 136 + colc] = __float2bfloat16(v);
            }
        }
        __syncthreads();
        // slab-layout write: 8 slabs x 128 rows x 32 B = 2048 x 16 B chunks
#pragma unroll
        for (int i = 0; i < 4; ++i) {
            const int chunk = i * 512 + tid;
            const int slab = chunk >> 8;
            const int r    = (chunk >> 1) & 127;
            const int half = chunk & 1;
            if (base + r < M)
                *(float4*)((char*)out + ((size_t)slab * M + base + r) * 32 + half * 16) =
                    *(const float4*)(smem + r * 272 + slab * 32 + half * 16);
        }
    } else {
        float* tl = (float*)smem;              // stride 132 f32 = 528 B
#pragma unroll
        for (int ct = 0; ct < 8; ++ct) {
            const int colc = ct * 16 + l15;
            const float bv = bias[colc];
#pragma unroll
            for (int r = 0; r < 4; ++r) {
                float v = acc[ct][r] + bv;
                if (RELU) v = fmaxf(v, 0.f);
                tl[(rloc + r) * 132 + colc] = v;
            }
        }
        __syncthreads();
        // row-major fp32 out: 128 rows x 512 B
#pragma unroll
        for (int i = 0; i < 8; ++i) {
            const int chunk = i * 512 + tid;
            const int row = chunk >> 5;
            const int c   = chunk & 31;
            if (base + row < M)
                *(float4*)((char*)out + (size_t)(base + row) * 512 + c * 16) =
                    *(const float4*)(smem + row * 528 + c * 16);
        }
    }
}

// ---------------- launch ----------------

extern "C" void kernel_launch(void* const* d_in, const int* in_sizes, int n_in,
                              void* d_out, int out_size, void* d_ws, size_t ws_size,
                              hipStream_t stream) {
    const float* x       = (const float*)d_in[0];
    const int*   ei      = (const int*)d_in[1];
    const float* w_rel1  = (const float*)d_in[2];
    const float* w_root1 = (const float*)d_in[3];
    const float* b1      = (const float*)d_in[4];
    const float* w_rel2  = (const float*)d_in[5];
    const float* w_root2 = (const float*)d_in[6];
    const float* b2      = (const float*)d_in[7];
    const float* w_rel3  = (const float*)d_in[8];
    const float* w_root3 = (const float*)d_in[9];
    const float* b3      = (const float*)d_in[10];
    float* out = (float*)d_out;

    const int N = in_sizes[0] / 128;
    const int E = in_sizes[1] / 2;
    const int* src = ei;
    const int* dst = ei + E;

    // workspace layout (~84 MB)
    char* w = (char*)d_ws;
    auto alloc = [&](size_t bytes) {
        char* p = w;
        w += (bytes + 255) & ~(size_t)255;
        return p;
    };
    int*  col  = (int*)alloc((size_t)E * 4);            // 6.4 MB
    int*  rp   = (int*)alloc((size_t)(N + 1) * 4);      // 0.4 MB
    bf16* h1   = (bf16*)alloc((size_t)N * 128 * 2);     // 25.6 MB
    bf16* xbf  = (bf16*)alloc((size_t)N * 128 * 2);     // 25.6 MB (reused as h2)
    bf16* aggb = (bf16*)alloc((size_t)N * 128 * 2);     // 25.6 MB
    bf16* wsw1 = (bf16*)alloc(32768 * 2);               // 64 KB
    bf16* wsw2 = (bf16*)alloc(32768 * 2);
    bf16* wsw3 = (bf16*)alloc(32768 * 2);
    bf16* h2   = xbf;       // layer-2 output overwrites xbf (last read: layer-1 gemm)
    // CSR-build scratch aliases buffers written only AFTER the build completes:
    int*  T    = (int*)h1;                  // NB*GB ints (~306 KB) in h1's space
    int*  bsum = (int*)(h1 + 1024 * 1024);  // scan partials, past T
    int*  ebuf = (int*)aggb;                // E ints (6.4 MB) in aggb's space

    const int NB = (N + BSZ - 1) / BSZ;        // 391 buckets
    const int GB = (E + CHUNK - 1) / CHUNK;    // 196 sort blocks
    const int nT = NB * GB;                    // 76,636
    const int scanTBlocks = (nT + 255) / 256;  // 300 <= 512

    const int aggBlocks  = 8 * ((N + 127) / 128);
    const int gemmBlocks = (N + 127) / 128;
    const int cvtBlocks  = (N * 32 + 255) / 256;

    // prep (cvt + wsw) and bhist: independent work, one dispatch
    prep_bhist_kernel<<<cvtBlocks + 48 + GB, 256, 0, stream>>>(
        x, xbf, N * 32, cvtBlocks,
        w_rel1, w_root1, w_rel2, w_root2, w_rel3, w_root3,
        wsw1, wsw2, wsw3,
        dst, T, E, NB, GB);

    // CSR by dst: two-level counting sort (scan3 folded into consumers)
    scan1_kernel<<<scanTBlocks, 256, 0, stream>>>(T, T, bsum, nT);
    scan2_kernel<<<1, 512, 0, stream>>>(bsum, scanTBlocks);
    bscatter_kernel<<<GB, 256, 0, stream>>>(src, dst, T, bsum, ebuf, E, NB, GB);
    bbuild_kernel<<<NB, 256, 0, stream>>>(T, bsum, ebuf, rp, col, E, N, NB, GB);

    // layer 1
    agg_kernel<<<aggBlocks, 512, 0, stream>>>(xbf, rp, col, aggb, N);
    mfma_gemm_kernel<true, bf16><<<gemmBlocks, 512, 0, stream>>>(aggb, xbf, wsw1, b1, h1, N);
    // layer 2
    agg_kernel<<<aggBlocks, 512, 0, stream>>>(h1, rp, col, aggb, N);
    mfma_gemm_kernel<true, bf16><<<gemmBlocks, 512, 0, stream>>>(aggb, h1, wsw2, b2, h2, N);
    // layer 3
    agg_kernel<<<aggBlocks, 512, 0, stream>>>(h2, rp, col, aggb, N);
    mfma_gemm_kernel<false, float><<<gemmBlocks, 512, 0, stream>>>(aggb, h2, wsw3, b3, out, N);
}